// Round 15
// baseline (1276.561 us; speedup 1.0000x reference)
//
#include <hip/hip_runtime.h>

#define DIMN 8192
#define SEQ  1024
#define NHEAD 128

typedef __attribute__((ext_vector_type(8))) short bf16x8;
typedef __attribute__((ext_vector_type(4))) float f32x4;

#define MFMA16(a, b, c) __builtin_amdgcn_mfma_f32_16x16x32_bf16((a), (b), (c), 0, 0, 0)

__device__ __forceinline__ unsigned short f2bf(float f) {
  unsigned u = __float_as_uint(f);
  return (unsigned short)((u + 0x7FFFu + ((u >> 16) & 1u)) >> 16);
}
__device__ __forceinline__ unsigned pack2(float a, float b) {
  return (unsigned)f2bf(a) | ((unsigned)f2bf(b) << 16);
}
__device__ __forceinline__ unsigned pack2_rhu(float lo, float hi) {
  unsigned a = __float_as_uint(lo) + 0x8000u;
  unsigned b = __float_as_uint(hi) + 0x8000u;
  return (a >> 16) | (b & 0xFFFF0000u);
}
__device__ __forceinline__ unsigned short f2bf_rhu(float f) {
  return (unsigned short)((__float_as_uint(f) + 0x8000u) >> 16);
}
__device__ __forceinline__ void async_copy16(void* lds_dst, const void* gsrc) {
  __builtin_amdgcn_global_load_lds(
      (const __attribute__((address_space(1))) unsigned int*)gsrc,
      (__attribute__((address_space(3))) unsigned int*)lds_dst, 16, 0, 0);
}

// ---------------- fp32 -> bf16 convert (x) ----------------
__global__ __launch_bounds__(256) void cvt_bf16_kernel(
    const float* __restrict__ in, unsigned short* __restrict__ out) {
  int i = blockIdx.x * 256 + threadIdx.x;
  const float4* p = (const float4*)in;
  float4 a = p[2 * i];
  float4 b = p[2 * i + 1];
  uint4 r;
  r.x = pack2(a.x, a.y);
  r.y = pack2(a.z, a.w);
  r.z = pack2(b.x, b.y);
  r.w = pack2(b.z, b.w);
  ((uint4*)out)[i] = r;
}

// ------------- W[k][n] fp32 -> Wt[n][k] bf16 (v2, unchanged) -------------
__global__ __launch_bounds__(256) void transpose_cvt_kernel(
    const float* __restrict__ W, unsigned short* __restrict__ Wt) {
  __shared__ unsigned short T[64 * 72];
  const int t = threadIdx.x;
  const int k0 = (blockIdx.x & 127) * 64;
  const int n0 = (blockIdx.x >> 7) * 64;
  const int slot = t & 7;
  const int kr = t >> 3;
#pragma unroll
  for (int pass = 0; pass < 2; ++pass) {
    int k = kr + pass * 32;
    const float* src = &W[(size_t)(k0 + k) * DIMN + n0 + slot * 8];
    float4 a = *(const float4*)src;
    float4 b = *(const float4*)(src + 4);
    uint4 r;
    r.x = pack2_rhu(a.x, a.y);
    r.y = pack2_rhu(a.z, a.w);
    r.z = pack2_rhu(b.x, b.y);
    r.w = pack2_rhu(b.z, b.w);
    *(uint4*)&T[k * 72 + slot * 8] = r;
  }
  __syncthreads();
  const int n = 4 * ((t >> 2) & 15) + (t >> 6);
  const int c = (t & 3) * 16;
  unsigned short tmp[16];
#pragma unroll
  for (int j = 0; j < 16; ++j) tmp[j] = T[(c + j) * 72 + n];
  uint4* dst = (uint4*)&Wt[(size_t)(n0 + n) * DIMN + k0 + c];
  dst[0] = *(uint4*)&tmp[0];
  dst[1] = *(uint4*)&tmp[8];
}

// ---------------- split-K pure-DMA GEMM ----------------
// R14 DIAGNOSIS: gemm_dma at 875 TF = m97-family ceiling; LDS fragment reads
// (ratio 0.5 b128/MFMA) + 2 blocks/CU (grid 512 = hard cap from M=1024) bind.
// FIX: split-K x2 -> grid 1024; BK=32 -> LDS 32KB -> 4 blocks/CU, 16 waves/CU.
// BK=32 rows are 64B: fragment reads/DMA stay conflict-free via source
// pre-swizzle slot^((row>>1)&3) (bank-verified: writes & reads at 8-access
// minimum). fp32 partials to ws; reduce kernel adds + packs.
// XCD swizzle: XCD x owns n-panels [8x,8x+8); all 16 sharers (8m x 2ks)
// of a panel co-resident per XCD.
__global__ __launch_bounds__(256, 4) void gemm_sk(
    const unsigned short* __restrict__ A, const unsigned short* __restrict__ Wt,
    float* __restrict__ P, float out_scale) {
  __shared__ unsigned short smem[2 * 8192];  // per buf: A[128][32] + B[128][32]
  const int t = threadIdx.x;
  const int l = t & 63;
  const int w = t >> 6;
  const int wm = w >> 1, wn = w & 1;
  const int logical = (blockIdx.x & 7) * 128 + (blockIdx.x >> 3);
  const int m0 = (logical & 7) * 128;
  const int ks = (logical >> 3) & 1;
  const int n0 = (logical >> 4) * 128;

  // DMA geometry: instr = 16 rows x 4 slots(16B); lane: row=l>>2, slot=l&3;
  // source pre-swizzled so LDS[row][p] holds source slot p^((row>>1)&3).
  const int drow = l >> 2;
  const int dslot = (l & 3) ^ ((l >> 3) & 3);

  f32x4 acc[4][4];
#pragma unroll
  for (int mb = 0; mb < 4; ++mb)
#pragma unroll
    for (int nb = 0; nb < 4; ++nb) acc[mb][nb] = (f32x4){0.f, 0.f, 0.f, 0.f};

  const unsigned short* aptr = A  + (size_t)(m0 + w * 32 + drow) * DIMN + ks * 4096 + dslot * 8;
  const unsigned short* bptr = Wt + (size_t)(n0 + w * 32 + drow) * DIMN + ks * 4096 + dslot * 8;

  auto stage = [&](int buf) {  // 4 DMA per wave (2 A + 2 B), advance k by 32
    unsigned short* sa = &smem[buf * 8192];
    unsigned short* sb = sa + 4096;
#pragma unroll
    for (int i = 0; i < 2; ++i)
      async_copy16(&sa[(w * 32 + i * 16) * 32], aptr + (size_t)i * 16 * DIMN);
#pragma unroll
    for (int i = 0; i < 2; ++i)
      async_copy16(&sb[(w * 32 + i * 16) * 32], bptr + (size_t)i * 16 * DIMN);
    aptr += 32;
    bptr += 32;
  };
  auto compute = [&](int buf) {  // 8 ds_read_b128 + 16 MFMA per wave
    const unsigned short* la = &smem[buf * 8192];
    const unsigned short* lb = la + 4096;
    bf16x8 af[4], bf[4];
#pragma unroll
    for (int mb = 0; mb < 4; ++mb) {
      int row = wm * 64 + mb * 16 + (l & 15);
      int p = (l >> 4) ^ (((l & 15) >> 1) & 3);
      af[mb] = *(const bf16x8*)&la[row * 32 + p * 8];
    }
#pragma unroll
    for (int nb = 0; nb < 4; ++nb) {
      int row = wn * 64 + nb * 16 + (l & 15);
      int p = (l >> 4) ^ (((l & 15) >> 1) & 3);
      bf[nb] = *(const bf16x8*)&lb[row * 32 + p * 8];
    }
    __builtin_amdgcn_s_setprio(1);
#pragma unroll
    for (int mb = 0; mb < 4; ++mb)
#pragma unroll
      for (int nb = 0; nb < 4; ++nb)
        acc[mb][nb] = MFMA16(af[mb], bf[nb], acc[mb][nb]);
    __builtin_amdgcn_s_setprio(0);
  };

  stage(0);
  __syncthreads();
  int buf = 0;
  for (int kt = 0; kt < 128; ++kt) {   // 128 K-tiles of 32 (K-half = 4096)
    if (kt < 127) stage(buf ^ 1);
    compute(buf);
    __syncthreads();
    buf ^= 1;
  }

  // partial store (fp32, scale folded; sum of scaled halves == scaled sum)
  float* Pk = P + (size_t)ks * SEQ * DIMN;
#pragma unroll
  for (int mb = 0; mb < 4; ++mb)
#pragma unroll
    for (int nb = 0; nb < 4; ++nb)
#pragma unroll
      for (int r = 0; r < 4; ++r) {
        int rg = m0 + wm * 64 + mb * 16 + (l >> 4) * 4 + r;
        int cg = n0 + wn * 64 + nb * 16 + (l & 15);
        Pk[(size_t)rg * DIMN + cg] = acc[mb][nb][r] * out_scale;
      }
}

// reduce: out = p0 + p1 (8M elems); bf16 or f32 out
__global__ __launch_bounds__(256) void reduce_bf16_kernel(
    const float* __restrict__ P, unsigned short* __restrict__ out) {
  int i = blockIdx.x * 256 + threadIdx.x;  // 1M threads x 8 elems
  const float4* p0 = (const float4*)P;
  const float4* p1 = (const float4*)(P + (size_t)SEQ * DIMN);
  float4 a0 = p0[2 * i], a1 = p0[2 * i + 1];
  float4 b0 = p1[2 * i], b1 = p1[2 * i + 1];
  uint4 r;
  r.x = pack2_rhu(a0.x + b0.x, a0.y + b0.y);
  r.y = pack2_rhu(a0.z + b0.z, a0.w + b0.w);
  r.z = pack2_rhu(a1.x + b1.x, a1.y + b1.y);
  r.w = pack2_rhu(a1.z + b1.z, a1.w + b1.w);
  ((uint4*)out)[i] = r;
}
__global__ __launch_bounds__(256) void reduce_f32_kernel(
    const float* __restrict__ P, float* __restrict__ out) {
  int i = blockIdx.x * 256 + threadIdx.x;  // 2M threads x 4 elems
  const float4* p0 = (const float4*)P;
  const float4* p1 = (const float4*)(P + (size_t)SEQ * DIMN);
  float4 a = p0[i], b = p1[i];
  float4 r = {a.x + b.x, a.y + b.y, a.z + b.z, a.w + b.w};
  ((float4*)out)[i] = r;
}

// ---------------- pure-DMA GEMM (R12 fallback when no partial space) ----------------
template <int WRITE_F32>
__global__ __launch_bounds__(256, 2) void gemm_dma(
    const unsigned short* __restrict__ A, const unsigned short* __restrict__ Wt,
    void* __restrict__ Cout, float out_scale) {
  __shared__ unsigned short smem[2 * 16384];
  const int t = threadIdx.x;
  const int l = t & 63;
  const int w = t >> 6;
  const int wm = w >> 1, wn = w & 1;
  const int logical = (blockIdx.x & 7) * 64 + (blockIdx.x >> 3);
  const int m0 = (logical & 7) * 128;
  const int n0 = (logical >> 3) * 128;
  const int rin = l >> 3;
  const int aslot = (l & 7) ^ rin;

  f32x4 acc[4][4];
#pragma unroll
  for (int mb = 0; mb < 4; ++mb)
#pragma unroll
    for (int nb = 0; nb < 4; ++nb) acc[mb][nb] = (f32x4){0.f, 0.f, 0.f, 0.f};

  const unsigned short* aptr = A  + (size_t)(m0 + w * 32 + rin) * DIMN + aslot * 8;
  const unsigned short* bptr = Wt + (size_t)(n0 + w * 32 + rin) * DIMN + aslot * 8;

  auto stage = [&](int buf) {
    unsigned short* sa = &smem[buf * 16384];
    unsigned short* sb = sa + 8192;
#pragma unroll
    for (int i = 0; i < 4; ++i)
      async_copy16(&sa[(w * 32 + i * 8) * 64], aptr + (size_t)i * 8 * DIMN);
#pragma unroll
    for (int i = 0; i < 4; ++i)
      async_copy16(&sb[(w * 32 + i * 8) * 64], bptr + (size_t)i * 8 * DIMN);
    aptr += 64;
    bptr += 64;
  };
  auto compute = [&](int buf) {
    const unsigned short* la = &smem[buf * 16384];
    const unsigned short* lb = la + 8192;
#pragma unroll
    for (int kh = 0; kh < 2; ++kh) {
      bf16x8 af[4], bf[4];
#pragma unroll
      for (int mb = 0; mb < 4; ++mb) {
        int row = wm * 64 + mb * 16 + (l & 15);
        int sl = ((l >> 4) + kh * 4) ^ (row & 7);
        af[mb] = *(const bf16x8*)&la[row * 64 + sl * 8];
      }
#pragma unroll
      for (int nb = 0; nb < 4; ++nb) {
        int row = wn * 64 + nb * 16 + (l & 15);
        int sl = ((l >> 4) + kh * 4) ^ (row & 7);
        bf[nb] = *(const bf16x8*)&lb[row * 64 + sl * 8];
      }
      __builtin_amdgcn_s_setprio(1);
#pragma unroll
      for (int mb = 0; mb < 4; ++mb)
#pragma unroll
        for (int nb = 0; nb < 4; ++nb)
          acc[mb][nb] = MFMA16(af[mb], bf[nb], acc[mb][nb]);
      __builtin_amdgcn_s_setprio(0);
    }
  };

  stage(0);
  __syncthreads();
  int buf = 0;
  for (int kt = 0; kt < 128; ++kt) {
    if (kt < 127) stage(buf ^ 1);
    compute(buf);
    __syncthreads();
    buf ^= 1;
  }

#pragma unroll
  for (int mb = 0; mb < 4; ++mb)
#pragma unroll
    for (int nb = 0; nb < 4; ++nb)
#pragma unroll
      for (int r = 0; r < 4; ++r) {
        int rg = m0 + wm * 64 + mb * 16 + (l >> 4) * 4 + r;
        int cg = n0 + wn * 64 + nb * 16 + (l & 15);
        float vl = acc[mb][nb][r] * out_scale;
        if (WRITE_F32)
          ((float*)Cout)[(size_t)rg * DIMN + cg] = vl;
        else
          ((unsigned short*)Cout)[(size_t)rg * DIMN + cg] = f2bf(vl);
      }
}

// ---------------- fallback GEMM (R11 reg-staging) — ws too small for Wt ----
template <int WRITE_F32>
__global__ __launch_bounds__(256, 3) void gemm_fb(
    const unsigned short* __restrict__ A, const float* __restrict__ W,
    void* __restrict__ Cout, float out_scale) {
  __shared__ unsigned short smem[2 * 8192];
  const int t = threadIdx.x;
  const int l = t & 63;
  const int w = t >> 6;
  const int wm = w >> 1, wn = w & 1;
  const int logical = (blockIdx.x & 7) * 64 + (blockIdx.x >> 3);
  const int m0 = (logical & 7) * 128;
  const int n0 = (logical >> 3) * 128;
  const int arow = l >> 2;
  const int aslot = l & 3;
  const int bn = t & 127;
  const int bkb = (t >> 7) * 16;

  f32x4 acc[4][4];
#pragma unroll
  for (int mb = 0; mb < 4; ++mb)
#pragma unroll
    for (int nb = 0; nb < 4; ++nb) acc[mb][nb] = (f32x4){0.f, 0.f, 0.f, 0.f};

  float fb[16];
  const unsigned short* aptr = A + (size_t)(m0 + w * 32 + arow) * DIMN + aslot * 8;
  const float* wp = W + (size_t)bkb * DIMN + n0 + bn;

  auto load_B = [&]() {
#pragma unroll
    for (int i = 0; i < 16; ++i) fb[i] = wp[(size_t)i * DIMN];
    wp += (size_t)32 * DIMN;
  };
  auto write_B = [&](int buf) {
    unsigned short* bb = &smem[buf * 8192 + 4096];
    const int ps = (bn >> 1) & 3;
#pragma unroll
    for (int j = 0; j < 2; ++j) {
      int p = ((bkb >> 3) + j) ^ ps;
      uint4 val;
      val.x = pack2_rhu(fb[j * 8 + 0], fb[j * 8 + 1]);
      val.y = pack2_rhu(fb[j * 8 + 2], fb[j * 8 + 3]);
      val.z = pack2_rhu(fb[j * 8 + 4], fb[j * 8 + 5]);
      val.w = pack2_rhu(fb[j * 8 + 6], fb[j * 8 + 7]);
      *(uint4*)&bb[bn * 32 + p * 8] = val;
    }
  };
  auto stage_A = [&](int buf) {
#pragma unroll
    for (int i = 0; i < 2; ++i)
      async_copy16(&smem[buf * 8192 + (w * 32 + i * 16) * 32],
                   aptr + (size_t)i * 16 * DIMN);
    aptr += 32;
  };
  auto compute = [&](int buf) {
    const unsigned short* la = &smem[buf * 8192];
    const unsigned short* lb = la + 4096;
    bf16x8 af[4], bf[4];
#pragma unroll
    for (int mb = 0; mb < 4; ++mb) {
      int row = wm * 64 + mb * 16 + (l & 15);
      af[mb] = *(const bf16x8*)&la[row * 32 + (l >> 4) * 8];
    }
#pragma unroll
    for (int nb = 0; nb < 4; ++nb) {
      int row = wn * 64 + nb * 16 + (l & 15);
      int p = (l >> 4) ^ ((row >> 1) & 3);
      bf[nb] = *(const bf16x8*)&lb[row * 32 + p * 8];
    }
#pragma unroll
    for (int mb = 0; mb < 4; ++mb)
#pragma unroll
      for (int nb = 0; nb < 4; ++nb)
        acc[mb][nb] = MFMA16(af[mb], bf[nb], acc[mb][nb]);
  };

  load_B();
  stage_A(0);
  write_B(0);
  __syncthreads();
  int buf = 0;
  for (int kt = 0; kt < 256; ++kt) {
    if (kt < 255) {
      load_B();
      stage_A(buf ^ 1);
    }
    compute(buf);
    if (kt < 255) write_B(buf ^ 1);
    __syncthreads();
    buf ^= 1;
  }
#pragma unroll
  for (int mb = 0; mb < 4; ++mb)
#pragma unroll
    for (int nb = 0; nb < 4; ++nb)
#pragma unroll
      for (int r = 0; r < 4; ++r) {
        int rg = m0 + wm * 64 + mb * 16 + (l >> 4) * 4 + r;
        int cg = n0 + wn * 64 + nb * 16 + (l & 15);
        float vl = acc[mb][nb][r] * out_scale;
        if (WRITE_F32)
          ((float*)Cout)[(size_t)rg * DIMN + cg] = vl;
        else
          ((unsigned short*)Cout)[(size_t)rg * DIMN + cg] = f2bf(vl);
      }
}

// ---------------- fused flash attention v2 (unchanged) ----------------
__global__ __launch_bounds__(256) void attn_kernel(
    const unsigned short* __restrict__ q, const unsigned short* __restrict__ k,
    const unsigned short* __restrict__ v, unsigned short* __restrict__ o) {
  __shared__ unsigned short Qs[64 * 64];
  __shared__ unsigned short Ks[2][64 * 64];
  __shared__ unsigned short Vt[64 * 72];
  __shared__ unsigned short Ps[4][16 * 72];

  const int t = threadIdx.x, l = t & 63, w = t >> 6;
  const int logical = (blockIdx.x & 7) * 256 + (blockIdx.x >> 3);
  const int h = logical >> 4;
  const int q0 = (logical & 15) * 64;

  const int rin = l >> 3;
  const int aslot = (l & 7) ^ rin;
  const int skey = t >> 2;
  const int sd = (t & 3) * 16;

  const unsigned short* qsrc = q + (size_t)(q0 + w * 16 + rin) * DIMN + h * 64 + aslot * 8;
  const unsigned short* ksrc = k + (size_t)(w * 16 + rin) * DIMN + h * 64 + aslot * 8;
  const unsigned short* vsrc = v + (size_t)skey * DIMN + h * 64 + sd;

  auto kdma = [&](int buf, int kv) {
#pragma unroll
    for (int i = 0; i < 2; ++i)
      async_copy16(&Ks[buf][(w * 16 + i * 8) * 64],
                   ksrc + (size_t)(kv * 64 + i * 8) * DIMN);
  };
  uint4 va0, va1, vb0, vb1;
  auto vload = [&](uint4& r0, uint4& r1, int kv) {
    const unsigned short* p = vsrc + (size_t)(kv * 64) * DIMN;
    r0 = *(const uint4*)p;
    r1 = *(const uint4*)(p + 8);
  };
  auto vwrite = [&](const uint4& r0, const uint4& r1) {
    const unsigned short* cs = (const unsigned short*)&r0;
    const unsigned short* ds = (const unsigned short*)&r1;
#pragma unroll
    for (int j = 0; j < 8; ++j) {
      int row = sd + j;
      Vt[row * 72 + (((skey >> 3) ^ ((row >> 3) & 7)) << 3) + (skey & 7)] = cs[j];
    }
#pragma unroll
    for (int j = 0; j < 8; ++j) {
      int row = sd + 8 + j;
      Vt[row * 72 + (((skey >> 3) ^ ((row >> 3) & 7)) << 3) + (skey & 7)] = ds[j];
    }
  };

  float m_run[4] = {-1e30f, -1e30f, -1e30f, -1e30f};
  float l_run[4] = {0.f, 0.f, 0.f, 0.f};
  f32x4 oacc[4];
#pragma unroll
  for (int db = 0; db < 4; ++db) oacc[db] = (f32x4){0.f, 0.f, 0.f, 0.f};

#pragma unroll
  for (int i = 0; i < 2; ++i)
    async_copy16(&Qs[(w * 16 + i * 8) * 64], qsrc + (size_t)(i * 8) * DIMN);
  kdma(0, 0);
  vload(va0, va1, 0);
  __syncthreads();

  bf16x8 qf[2];
#pragma unroll
  for (int kh = 0; kh < 2; ++kh) {
    int row = w * 16 + (l & 15);
    int s = (l >> 4) + kh * 4;
    qf[kh] = *(const bf16x8*)&Qs[row * 64 + (s ^ (row & 7)) * 8];
  }

  auto compute = [&](int kbuf) {
    f32x4 sAcc[4];
#pragma unroll
    for (int nb = 0; nb < 4; ++nb) sAcc[nb] = (f32x4){0.f, 0.f, 0.f, 0.f};
#pragma unroll
    for (int kh = 0; kh < 2; ++kh) {
      bf16x8 kf[4];
#pragma unroll
      for (int nb = 0; nb < 4; ++nb) {
        int row = nb * 16 + (l & 15);
        int s = (l >> 4) + kh * 4;
        kf[nb] = *(const bf16x8*)&Ks[kbuf][row * 64 + (s ^ (row & 7)) * 8];
      }
      __builtin_amdgcn_s_setprio(1);
#pragma unroll
      for (int nb = 0; nb < 4; ++nb) sAcc[nb] = MFMA16(qf[kh], kf[nb], sAcc[nb]);
      __builtin_amdgcn_s_setprio(0);
    }
    float sc[4], mx[4];
#pragma unroll
    for (int r = 0; r < 4; ++r) {
      float mv = fmaxf(fmaxf(sAcc[0][r], sAcc[1][r]), fmaxf(sAcc[2][r], sAcc[3][r]));
      mv = fmaxf(mv, __shfl_xor(mv, 1));
      mv = fmaxf(mv, __shfl_xor(mv, 2));
      mv = fmaxf(mv, __shfl_xor(mv, 4));
      mv = fmaxf(mv, __shfl_xor(mv, 8));
      float mn = fmaxf(m_run[r], mv);
      sc[r] = __expf(m_run[r] - mn);
      m_run[r] = mn;
      mx[r] = mn;
    }
#pragma unroll
    for (int nb = 0; nb < 4; ++nb) {
      f32x4 sv = sAcc[nb];
#pragma unroll
      for (int r = 0; r < 4; ++r) sv[r] = __expf(sv[r] - mx[r]);
      sAcc[nb] = sv;
    }
#pragma unroll
    for (int r = 0; r < 4; ++r) {
      float ls = sAcc[0][r] + sAcc[1][r] + sAcc[2][r] + sAcc[3][r];
      ls += __shfl_xor(ls, 1);
      ls += __shfl_xor(ls, 2);
      ls += __shfl_xor(ls, 4);
      ls += __shfl_xor(ls, 8);
      l_run[r] = l_run[r] * sc[r] + ls;
    }
#pragma unroll
    for (int db = 0; db < 4; ++db) {
      f32x4 ov = oacc[db];
#pragma unroll
      for (int r = 0; r < 4; ++r) ov[r] *= sc[r];
      oacc[db] = ov;
    }
#pragma unroll
    for (int nb = 0; nb < 4; ++nb)
#pragma unroll
      for (int r = 0; r < 4; ++r)
        Ps[w][((l >> 4) * 4 + r) * 72 + nb * 16 + (l & 15)] = f2bf_rhu(sAcc[nb][r]);
#pragma unroll
    for (int kh = 0; kh < 2; ++kh) {
      bf16x8 pf = *(const bf16x8*)&Ps[w][(l & 15) * 72 + (l >> 4) * 8 + kh * 32];
      bf16x8 vf[4];
#pragma unroll
      for (int db = 0; db < 4; ++db) {
        int R = db * 16 + (l & 15);
        int s = (l >> 4) + kh * 4;
        vf[db] = *(const bf16x8*)&Vt[R * 72 + (s ^ ((R >> 3) & 7)) * 8];
      }
      __builtin_amdgcn_s_setprio(1);
#pragma unroll
      for (int db = 0; db < 4; ++db) oacc[db] = MFMA16(pf, vf[db], oacc[db]);
      __builtin_amdgcn_s_setprio(0);
    }
  };

  for (int it = 0; it < 8; ++it) {
    int t0 = 2 * it;
    vwrite(va0, va1);
    __syncthreads();
    kdma(1, t0 + 1);
    vload(vb0, vb1, t0 + 1);
    compute(0);
    __syncthreads();
    vwrite(vb0, vb1);
    __syncthreads();
    if (it < 7) {
      kdma(0, t0 + 2);
      vload(va0, va1, t0 + 2);
    }
    compute(1);
    __syncthreads();
  }

#pragma unroll
  for (int db = 0; db < 4; ++db)
#pragma unroll
    for (int r = 0; r < 4; ++r) {
      float vl = oacc[db][r] / l_run[r];
      int rg = q0 + w * 16 + (l >> 4) * 4 + r;
      int cg = h * 64 + db * 16 + (l & 15);
      o[(size_t)rg * DIMN + cg] = f2bf(vl);
    }
}

extern "C" void kernel_launch(void* const* d_in, const int* in_sizes, int n_in,
                              void* d_out, int out_size, void* d_ws, size_t ws_size,
                              hipStream_t stream) {
  const float* x  = (const float*)d_in[0];
  const float* wq = (const float*)d_in[1];
  const float* wk = (const float*)d_in[2];
  const float* wv = (const float*)d_in[3];
  const float* wo = (const float*)d_in[4];

  char* ws = (char*)d_ws;
  const size_t MB16 = (size_t)16 * 1024 * 1024;
  unsigned short* xb = (unsigned short*)(ws);
  unsigned short* qb = (unsigned short*)(ws + 1 * MB16);
  unsigned short* kb = (unsigned short*)(ws + 2 * MB16);
  unsigned short* vb = (unsigned short*)(ws + 3 * MB16);
  unsigned short* ab = (unsigned short*)(ws + 4 * MB16);
  unsigned short* Wt = (unsigned short*)(ws + 5 * MB16);   // 128 MB
  float* Pp = (float*)(ws + 5 * MB16 + (size_t)DIMN * DIMN * 2);  // 64 MB partials

  const size_t WT_BYTES = (size_t)DIMN * DIMN * 2;
  const size_t NEED_DMA = 5 * MB16 + WT_BYTES;                       // ~208 MB
  const size_t NEED_SK  = NEED_DMA + (size_t)2 * SEQ * DIMN * 4;    // ~272 MB

  cvt_bf16_kernel<<<4096, 256, 0, stream>>>(x, xb);

  if (ws_size >= NEED_SK) {
    // split-K path: 4 blocks/CU GEMM + reduce
    transpose_cvt_kernel<<<16384, 256, 0, stream>>>(wq, Wt);
    gemm_sk<<<1024, 256, 0, stream>>>(xb, Wt, Pp, 0.125f);
    reduce_bf16_kernel<<<4096, 256, 0, stream>>>(Pp, qb);
    transpose_cvt_kernel<<<16384, 256, 0, stream>>>(wk, Wt);
    gemm_sk<<<1024, 256, 0, stream>>>(xb, Wt, Pp, 1.0f);
    reduce_bf16_kernel<<<4096, 256, 0, stream>>>(Pp, kb);
    transpose_cvt_kernel<<<16384, 256, 0, stream>>>(wv, Wt);
    gemm_sk<<<1024, 256, 0, stream>>>(xb, Wt, Pp, 1.0f);
    reduce_bf16_kernel<<<4096, 256, 0, stream>>>(Pp, vb);
    attn_kernel<<<2048, 256, 0, stream>>>(qb, kb, vb, ab);
    transpose_cvt_kernel<<<16384, 256, 0, stream>>>(wo, Wt);
    gemm_sk<<<1024, 256, 0, stream>>>(ab, Wt, Pp, 1.0f);
    reduce_f32_kernel<<<8192, 256, 0, stream>>>(Pp, (float*)d_out);
  } else if (ws_size >= NEED_DMA) {
    transpose_cvt_kernel<<<16384, 256, 0, stream>>>(wq, Wt);
    gemm_dma<0><<<512, 256, 0, stream>>>(xb, Wt, qb, 0.125f);
    transpose_cvt_kernel<<<16384, 256, 0, stream>>>(wk, Wt);
    gemm_dma<0><<<512, 256, 0, stream>>>(xb, Wt, kb, 1.0f);
    transpose_cvt_kernel<<<16384, 256, 0, stream>>>(wv, Wt);
    gemm_dma<0><<<512, 256, 0, stream>>>(xb, Wt, vb, 1.0f);
    attn_kernel<<<2048, 256, 0, stream>>>(qb, kb, vb, ab);
    transpose_cvt_kernel<<<16384, 256, 0, stream>>>(wo, Wt);
    gemm_dma<1><<<512, 256, 0, stream>>>(ab, Wt, d_out, 1.0f);
  } else {
    gemm_fb<0><<<512, 256, 0, stream>>>(xb, wq, qb, 0.125f);
    gemm_fb<0><<<512, 256, 0, stream>>>(xb, wk, kb, 1.0f);
    gemm_fb<0><<<512, 256, 0, stream>>>(xb, wv, vb, 1.0f);
    attn_kernel<<<2048, 256, 0, stream>>>(qb, kb, vb, ab);
    gemm_fb<1><<<512, 256, 0, stream>>>(ab, wo, d_out, 1.0f);
  }
}

// Round 16
// 1060.603 us; speedup vs baseline: 1.2036x; 1.2036x over previous
//
#include <hip/hip_runtime.h>

#define DIMN 8192
#define SEQ  1024
#define NHEAD 128

typedef __attribute__((ext_vector_type(8))) short bf16x8;
typedef __attribute__((ext_vector_type(4))) float f32x4;

#define MFMA16(a, b, c) __builtin_amdgcn_mfma_f32_16x16x32_bf16((a), (b), (c), 0, 0, 0)

__device__ __forceinline__ unsigned short f2bf(float f) {
  unsigned u = __float_as_uint(f);
  return (unsigned short)((u + 0x7FFFu + ((u >> 16) & 1u)) >> 16);
}
__device__ __forceinline__ unsigned pack2(float a, float b) {
  return (unsigned)f2bf(a) | ((unsigned)f2bf(b) << 16);
}
__device__ __forceinline__ unsigned pack2_rhu(float lo, float hi) {
  unsigned a = __float_as_uint(lo) + 0x8000u;
  unsigned b = __float_as_uint(hi) + 0x8000u;
  return (a >> 16) | (b & 0xFFFF0000u);
}
__device__ __forceinline__ unsigned short f2bf_rhu(float f) {
  return (unsigned short)((__float_as_uint(f) + 0x8000u) >> 16);
}
__device__ __forceinline__ void async_copy16(void* lds_dst, const void* gsrc) {
  __builtin_amdgcn_global_load_lds(
      (const __attribute__((address_space(1))) unsigned int*)gsrc,
      (__attribute__((address_space(3))) unsigned int*)lds_dst, 16, 0, 0);
}

// ---------------- fp32 -> bf16 convert (x) ----------------
__global__ __launch_bounds__(256) void cvt_bf16_kernel(
    const float* __restrict__ in, unsigned short* __restrict__ out) {
  int i = blockIdx.x * 256 + threadIdx.x;
  const float4* p = (const float4*)in;
  float4 a = p[2 * i];
  float4 b = p[2 * i + 1];
  uint4 r;
  r.x = pack2(a.x, a.y);
  r.y = pack2(a.z, a.w);
  r.z = pack2(b.x, b.y);
  r.w = pack2(b.z, b.w);
  ((uint4*)out)[i] = r;
}

// ------------- W[k][n] fp32 -> Wt[n][k] bf16 (v2, unchanged) -------------
__global__ __launch_bounds__(256) void transpose_cvt_kernel(
    const float* __restrict__ W, unsigned short* __restrict__ Wt) {
  __shared__ unsigned short T[64 * 72];
  const int t = threadIdx.x;
  const int k0 = (blockIdx.x & 127) * 64;
  const int n0 = (blockIdx.x >> 7) * 64;
  const int slot = t & 7;
  const int kr = t >> 3;
#pragma unroll
  for (int pass = 0; pass < 2; ++pass) {
    int k = kr + pass * 32;
    const float* src = &W[(size_t)(k0 + k) * DIMN + n0 + slot * 8];
    float4 a = *(const float4*)src;
    float4 b = *(const float4*)(src + 4);
    uint4 r;
    r.x = pack2_rhu(a.x, a.y);
    r.y = pack2_rhu(a.z, a.w);
    r.z = pack2_rhu(b.x, b.y);
    r.w = pack2_rhu(b.z, b.w);
    *(uint4*)&T[k * 72 + slot * 8] = r;
  }
  __syncthreads();
  const int n = 4 * ((t >> 2) & 15) + (t >> 6);
  const int c = (t & 3) * 16;
  unsigned short tmp[16];
#pragma unroll
  for (int j = 0; j < 16; ++j) tmp[j] = T[(c + j) * 72 + n];
  uint4* dst = (uint4*)&Wt[(size_t)(n0 + n) * DIMN + k0 + c];
  dst[0] = *(uint4*)&tmp[0];
  dst[1] = *(uint4*)&tmp[8];
}

// ---------------- pure-DMA GEMM (R14 verified: ~157us, 875 TF) ----------------
// R15 POST-MORTEM: split-K x2 regressed (199us + reduces; per-barrier compute
// halved, FETCH 2x) -> reverted to this verified structure.
template <int WRITE_F32>
__global__ __launch_bounds__(256, 2) void gemm_dma(
    const unsigned short* __restrict__ A, const unsigned short* __restrict__ Wt,
    void* __restrict__ Cout, float out_scale) {
  __shared__ unsigned short smem[2 * 16384];
  const int t = threadIdx.x;
  const int l = t & 63;
  const int w = t >> 6;
  const int wm = w >> 1, wn = w & 1;
  const int logical = (blockIdx.x & 7) * 64 + (blockIdx.x >> 3);
  const int m0 = (logical & 7) * 128;
  const int n0 = (logical >> 3) * 128;
  const int rin = l >> 3;
  const int aslot = (l & 7) ^ rin;

  f32x4 acc[4][4];
#pragma unroll
  for (int mb = 0; mb < 4; ++mb)
#pragma unroll
    for (int nb = 0; nb < 4; ++nb) acc[mb][nb] = (f32x4){0.f, 0.f, 0.f, 0.f};

  const unsigned short* aptr = A  + (size_t)(m0 + w * 32 + rin) * DIMN + aslot * 8;
  const unsigned short* bptr = Wt + (size_t)(n0 + w * 32 + rin) * DIMN + aslot * 8;

  auto stage = [&](int buf) {
    unsigned short* sa = &smem[buf * 16384];
    unsigned short* sb = sa + 8192;
#pragma unroll
    for (int i = 0; i < 4; ++i)
      async_copy16(&sa[(w * 32 + i * 8) * 64], aptr + (size_t)i * 8 * DIMN);
#pragma unroll
    for (int i = 0; i < 4; ++i)
      async_copy16(&sb[(w * 32 + i * 8) * 64], bptr + (size_t)i * 8 * DIMN);
    aptr += 64;
    bptr += 64;
  };
  auto compute = [&](int buf) {
    const unsigned short* la = &smem[buf * 16384];
    const unsigned short* lb = la + 8192;
#pragma unroll
    for (int kh = 0; kh < 2; ++kh) {
      bf16x8 af[4], bf[4];
#pragma unroll
      for (int mb = 0; mb < 4; ++mb) {
        int row = wm * 64 + mb * 16 + (l & 15);
        int sl = ((l >> 4) + kh * 4) ^ (row & 7);
        af[mb] = *(const bf16x8*)&la[row * 64 + sl * 8];
      }
#pragma unroll
      for (int nb = 0; nb < 4; ++nb) {
        int row = wn * 64 + nb * 16 + (l & 15);
        int sl = ((l >> 4) + kh * 4) ^ (row & 7);
        bf[nb] = *(const bf16x8*)&lb[row * 64 + sl * 8];
      }
      __builtin_amdgcn_s_setprio(1);
#pragma unroll
      for (int mb = 0; mb < 4; ++mb)
#pragma unroll
        for (int nb = 0; nb < 4; ++nb)
          acc[mb][nb] = MFMA16(af[mb], bf[nb], acc[mb][nb]);
      __builtin_amdgcn_s_setprio(0);
    }
  };

  stage(0);
  __syncthreads();
  int buf = 0;
  for (int kt = 0; kt < 128; ++kt) {
    if (kt < 127) stage(buf ^ 1);
    compute(buf);
    __syncthreads();
    buf ^= 1;
  }

#pragma unroll
  for (int mb = 0; mb < 4; ++mb)
#pragma unroll
    for (int nb = 0; nb < 4; ++nb)
#pragma unroll
      for (int r = 0; r < 4; ++r) {
        int rg = m0 + wm * 64 + mb * 16 + (l >> 4) * 4 + r;
        int cg = n0 + wn * 64 + nb * 16 + (l & 15);
        float vl = acc[mb][nb][r] * out_scale;
        if (WRITE_F32)
          ((float*)Cout)[(size_t)rg * DIMN + cg] = vl;
        else
          ((unsigned short*)Cout)[(size_t)rg * DIMN + cg] = f2bf(vl);
      }
}

// ---------------- fallback GEMM (R11 reg-staging) — ws too small for Wt ----
template <int WRITE_F32>
__global__ __launch_bounds__(256, 3) void gemm_fb(
    const unsigned short* __restrict__ A, const float* __restrict__ W,
    void* __restrict__ Cout, float out_scale) {
  __shared__ unsigned short smem[2 * 8192];
  const int t = threadIdx.x;
  const int l = t & 63;
  const int w = t >> 6;
  const int wm = w >> 1, wn = w & 1;
  const int logical = (blockIdx.x & 7) * 64 + (blockIdx.x >> 3);
  const int m0 = (logical & 7) * 128;
  const int n0 = (logical >> 3) * 128;
  const int arow = l >> 2;
  const int aslot = l & 3;
  const int bn = t & 127;
  const int bkb = (t >> 7) * 16;

  f32x4 acc[4][4];
#pragma unroll
  for (int mb = 0; mb < 4; ++mb)
#pragma unroll
    for (int nb = 0; nb < 4; ++nb) acc[mb][nb] = (f32x4){0.f, 0.f, 0.f, 0.f};

  float fb[16];
  const unsigned short* aptr = A + (size_t)(m0 + w * 32 + arow) * DIMN + aslot * 8;
  const float* wp = W + (size_t)bkb * DIMN + n0 + bn;

  auto load_B = [&]() {
#pragma unroll
    for (int i = 0; i < 16; ++i) fb[i] = wp[(size_t)i * DIMN];
    wp += (size_t)32 * DIMN;
  };
  auto write_B = [&](int buf) {
    unsigned short* bb = &smem[buf * 8192 + 4096];
    const int ps = (bn >> 1) & 3;
#pragma unroll
    for (int j = 0; j < 2; ++j) {
      int p = ((bkb >> 3) + j) ^ ps;
      uint4 val;
      val.x = pack2_rhu(fb[j * 8 + 0], fb[j * 8 + 1]);
      val.y = pack2_rhu(fb[j * 8 + 2], fb[j * 8 + 3]);
      val.z = pack2_rhu(fb[j * 8 + 4], fb[j * 8 + 5]);
      val.w = pack2_rhu(fb[j * 8 + 6], fb[j * 8 + 7]);
      *(uint4*)&bb[bn * 32 + p * 8] = val;
    }
  };
  auto stage_A = [&](int buf) {
#pragma unroll
    for (int i = 0; i < 2; ++i)
      async_copy16(&smem[buf * 8192 + (w * 32 + i * 16) * 32],
                   aptr + (size_t)i * 16 * DIMN);
    aptr += 32;
  };
  auto compute = [&](int buf) {
    const unsigned short* la = &smem[buf * 8192];
    const unsigned short* lb = la + 4096;
    bf16x8 af[4], bf[4];
#pragma unroll
    for (int mb = 0; mb < 4; ++mb) {
      int row = wm * 64 + mb * 16 + (l & 15);
      af[mb] = *(const bf16x8*)&la[row * 32 + (l >> 4) * 8];
    }
#pragma unroll
    for (int nb = 0; nb < 4; ++nb) {
      int row = wn * 64 + nb * 16 + (l & 15);
      int p = (l >> 4) ^ ((row >> 1) & 3);
      bf[nb] = *(const bf16x8*)&lb[row * 32 + p * 8];
    }
#pragma unroll
    for (int mb = 0; mb < 4; ++mb)
#pragma unroll
      for (int nb = 0; nb < 4; ++nb)
        acc[mb][nb] = MFMA16(af[mb], bf[nb], acc[mb][nb]);
  };

  load_B();
  stage_A(0);
  write_B(0);
  __syncthreads();
  int buf = 0;
  for (int kt = 0; kt < 256; ++kt) {
    if (kt < 255) {
      load_B();
      stage_A(buf ^ 1);
    }
    compute(buf);
    if (kt < 255) write_B(buf ^ 1);
    __syncthreads();
    buf ^= 1;
  }
#pragma unroll
  for (int mb = 0; mb < 4; ++mb)
#pragma unroll
    for (int nb = 0; nb < 4; ++nb)
#pragma unroll
      for (int r = 0; r < 4; ++r) {
        int rg = m0 + wm * 64 + mb * 16 + (l >> 4) * 4 + r;
        int cg = n0 + wn * 64 + nb * 16 + (l & 15);
        float vl = acc[mb][nb][r] * out_scale;
        if (WRITE_F32)
          ((float*)Cout)[(size_t)rg * DIMN + cg] = vl;
        else
          ((unsigned short*)Cout)[(size_t)rg * DIMN + cg] = f2bf(vl);
      }
}

// ---------------- fused flash attention v3: QBLK=128 ----------------
// R15 DIAGNOSIS: attn FETCH 139MB vs ~40 ideal (K/V re-fetched by 16 q-blocks
// per head, ~50% L2 absorption); MfmaUtil 9%. FIX: 2 q-tiles per block share
// each staged K/V tile -> K/V HBM traffic and K-DMA overhead per FLOP halved.
// Per-wave DS ordering lets Ps/Vt be reused across q-halves barrier-free.
// LDS: Qs 16K + Ks 2x8K + Vt 9K + Ps 9K = 50KB -> 3 blocks/CU. grid 1024;
// XCD swizzle: heads [16x,16x+16) on XCD x.
__global__ __launch_bounds__(256) void attn_kernel(
    const unsigned short* __restrict__ q, const unsigned short* __restrict__ k,
    const unsigned short* __restrict__ v, unsigned short* __restrict__ o) {
  __shared__ unsigned short Qs[128 * 64];
  __shared__ unsigned short Ks[2][64 * 64];
  __shared__ unsigned short Vt[64 * 72];
  __shared__ unsigned short Ps[4][16 * 72];

  const int t = threadIdx.x, l = t & 63, w = t >> 6;
  const int logical = (blockIdx.x & 7) * 128 + (blockIdx.x >> 3);  // XCD swizzle
  const int h = logical >> 3;
  const int q0 = (logical & 7) * 128;

  const int rin = l >> 3;
  const int aslot = (l & 7) ^ rin;
  const int skey = t >> 2;
  const int sd = (t & 3) * 16;

  const unsigned short* qsrc = q + (size_t)(q0 + w * 32 + rin) * DIMN + h * 64 + aslot * 8;
  const unsigned short* ksrc = k + (size_t)(w * 16 + rin) * DIMN + h * 64 + aslot * 8;
  const unsigned short* vsrc = v + (size_t)skey * DIMN + h * 64 + sd;

  auto kdma = [&](int buf, int kv) {
#pragma unroll
    for (int i = 0; i < 2; ++i)
      async_copy16(&Ks[buf][(w * 16 + i * 8) * 64],
                   ksrc + (size_t)(kv * 64 + i * 8) * DIMN);
  };
  uint4 va0, va1, vb0, vb1;
  auto vload = [&](uint4& r0, uint4& r1, int kv) {
    const unsigned short* p = vsrc + (size_t)(kv * 64) * DIMN;
    r0 = *(const uint4*)p;
    r1 = *(const uint4*)(p + 8);
  };
  auto vwrite = [&](const uint4& r0, const uint4& r1) {
    const unsigned short* cs = (const unsigned short*)&r0;
    const unsigned short* ds = (const unsigned short*)&r1;
#pragma unroll
    for (int j = 0; j < 8; ++j) {
      int row = sd + j;
      Vt[row * 72 + (((skey >> 3) ^ ((row >> 3) & 7)) << 3) + (skey & 7)] = cs[j];
    }
#pragma unroll
    for (int j = 0; j < 8; ++j) {
      int row = sd + 8 + j;
      Vt[row * 72 + (((skey >> 3) ^ ((row >> 3) & 7)) << 3) + (skey & 7)] = ds[j];
    }
  };

  // per-q-half state: wave w owns q-rows [q0 + w*32, q0 + w*32 + 32)
  float m_run[2][4], l_run[2][4];
  f32x4 oacc[2][4];
#pragma unroll
  for (int qh = 0; qh < 2; ++qh) {
#pragma unroll
    for (int r = 0; r < 4; ++r) { m_run[qh][r] = -1e30f; l_run[qh][r] = 0.f; }
#pragma unroll
    for (int db = 0; db < 4; ++db) oacc[qh][db] = (f32x4){0.f, 0.f, 0.f, 0.f};
  }

  // prologue: Q (128 rows) + K(0) DMA, V(0) regs
#pragma unroll
  for (int i = 0; i < 4; ++i)
    async_copy16(&Qs[(w * 32 + i * 8) * 64], qsrc + (size_t)(i * 8) * DIMN);
  kdma(0, 0);
  vload(va0, va1, 0);
  __syncthreads();

  bf16x8 qf[2][2];
#pragma unroll
  for (int qh = 0; qh < 2; ++qh)
#pragma unroll
    for (int kh = 0; kh < 2; ++kh) {
      int row = w * 32 + qh * 16 + (l & 15);
      int s = (l >> 4) + kh * 4;
      qf[qh][kh] = *(const bf16x8*)&Qs[row * 64 + (s ^ (row & 7)) * 8];
    }

  auto compute = [&](int kbuf) {
#pragma unroll
    for (int qh = 0; qh < 2; ++qh) {
      // S = Q K^T
      f32x4 sAcc[4];
#pragma unroll
      for (int nb = 0; nb < 4; ++nb) sAcc[nb] = (f32x4){0.f, 0.f, 0.f, 0.f};
#pragma unroll
      for (int kh = 0; kh < 2; ++kh) {
        bf16x8 kf[4];
#pragma unroll
        for (int nb = 0; nb < 4; ++nb) {
          int row = nb * 16 + (l & 15);
          int s = (l >> 4) + kh * 4;
          kf[nb] = *(const bf16x8*)&Ks[kbuf][row * 64 + (s ^ (row & 7)) * 8];
        }
        __builtin_amdgcn_s_setprio(1);
#pragma unroll
        for (int nb = 0; nb < 4; ++nb) sAcc[nb] = MFMA16(qf[qh][kh], kf[nb], sAcc[nb]);
        __builtin_amdgcn_s_setprio(0);
      }
      // online softmax
      float sc[4], mx[4];
#pragma unroll
      for (int r = 0; r < 4; ++r) {
        float mv = fmaxf(fmaxf(sAcc[0][r], sAcc[1][r]), fmaxf(sAcc[2][r], sAcc[3][r]));
        mv = fmaxf(mv, __shfl_xor(mv, 1));
        mv = fmaxf(mv, __shfl_xor(mv, 2));
        mv = fmaxf(mv, __shfl_xor(mv, 4));
        mv = fmaxf(mv, __shfl_xor(mv, 8));
        float mn = fmaxf(m_run[qh][r], mv);
        sc[r] = __expf(m_run[qh][r] - mn);
        m_run[qh][r] = mn;
        mx[r] = mn;
      }
#pragma unroll
      for (int nb = 0; nb < 4; ++nb) {
        f32x4 sv = sAcc[nb];
#pragma unroll
        for (int r = 0; r < 4; ++r) sv[r] = __expf(sv[r] - mx[r]);
        sAcc[nb] = sv;
      }
#pragma unroll
      for (int r = 0; r < 4; ++r) {
        float ls = sAcc[0][r] + sAcc[1][r] + sAcc[2][r] + sAcc[3][r];
        ls += __shfl_xor(ls, 1);
        ls += __shfl_xor(ls, 2);
        ls += __shfl_xor(ls, 4);
        ls += __shfl_xor(ls, 8);
        l_run[qh][r] = l_run[qh][r] * sc[r] + ls;
      }
#pragma unroll
      for (int db = 0; db < 4; ++db) {
        f32x4 ov = oacc[qh][db];
#pragma unroll
        for (int r = 0; r < 4; ++r) ov[r] *= sc[r];
        oacc[qh][db] = ov;
      }
      // P -> bf16 -> per-wave LDS (reused across qh: per-wave DS is in-order)
#pragma unroll
      for (int nb = 0; nb < 4; ++nb)
#pragma unroll
        for (int r = 0; r < 4; ++r)
          Ps[w][((l >> 4) * 4 + r) * 72 + nb * 16 + (l & 15)] = f2bf_rhu(sAcc[nb][r]);
      // O += P V
#pragma unroll
      for (int kh = 0; kh < 2; ++kh) {
        bf16x8 pf = *(const bf16x8*)&Ps[w][(l & 15) * 72 + (l >> 4) * 8 + kh * 32];
        bf16x8 vf[4];
#pragma unroll
        for (int db = 0; db < 4; ++db) {
          int R = db * 16 + (l & 15);
          int s = (l >> 4) + kh * 4;
          vf[db] = *(const bf16x8*)&Vt[R * 72 + (s ^ ((R >> 3) & 7)) * 8];
        }
        __builtin_amdgcn_s_setprio(1);
#pragma unroll
        for (int db = 0; db < 4; ++db) oacc[qh][db] = MFMA16(pf, vf[db], oacc[qh][db]);
        __builtin_amdgcn_s_setprio(0);
      }
    }
  };

  for (int it = 0; it < 8; ++it) {
    int t0 = 2 * it;
    vwrite(va0, va1);
    __syncthreads();
    kdma(1, t0 + 1);
    vload(vb0, vb1, t0 + 1);
    compute(0);
    __syncthreads();
    vwrite(vb0, vb1);
    __syncthreads();
    if (it < 7) {
      kdma(0, t0 + 2);
      vload(va0, va1, t0 + 2);
    }
    compute(1);
    __syncthreads();
  }

  // epilogue
#pragma unroll
  for (int qh = 0; qh < 2; ++qh)
#pragma unroll
    for (int db = 0; db < 4; ++db)
#pragma unroll
      for (int r = 0; r < 4; ++r) {
        float vl = oacc[qh][db][r] / l_run[qh][r];
        int rg = q0 + w * 32 + qh * 16 + (l >> 4) * 4 + r;
        int cg = h * 64 + db * 16 + (l & 15);
        o[(size_t)rg * DIMN + cg] = f2bf(vl);
      }
}

extern "C" void kernel_launch(void* const* d_in, const int* in_sizes, int n_in,
                              void* d_out, int out_size, void* d_ws, size_t ws_size,
                              hipStream_t stream) {
  const float* x  = (const float*)d_in[0];
  const float* wq = (const float*)d_in[1];
  const float* wk = (const float*)d_in[2];
  const float* wv = (const float*)d_in[3];
  const float* wo = (const float*)d_in[4];

  char* ws = (char*)d_ws;
  const size_t MB16 = (size_t)16 * 1024 * 1024;
  unsigned short* xb = (unsigned short*)(ws);
  unsigned short* qb = (unsigned short*)(ws + 1 * MB16);
  unsigned short* kb = (unsigned short*)(ws + 2 * MB16);
  unsigned short* vb = (unsigned short*)(ws + 3 * MB16);
  unsigned short* ab = (unsigned short*)(ws + 4 * MB16);
  unsigned short* Wt = (unsigned short*)(ws + 5 * MB16);  // 128 MB, reused serially

  const size_t WT_BYTES = (size_t)DIMN * DIMN * 2;
  const size_t NEED_DMA = 5 * MB16 + WT_BYTES;  // ~208 MB

  cvt_bf16_kernel<<<4096, 256, 0, stream>>>(x, xb);

  if (ws_size >= NEED_DMA) {
    transpose_cvt_kernel<<<16384, 256, 0, stream>>>(wq, Wt);
    gemm_dma<0><<<512, 256, 0, stream>>>(xb, Wt, qb, 0.125f);  // softmax scale folded
    transpose_cvt_kernel<<<16384, 256, 0, stream>>>(wk, Wt);
    gemm_dma<0><<<512, 256, 0, stream>>>(xb, Wt, kb, 1.0f);
    transpose_cvt_kernel<<<16384, 256, 0, stream>>>(wv, Wt);
    gemm_dma<0><<<512, 256, 0, stream>>>(xb, Wt, vb, 1.0f);
    attn_kernel<<<1024, 256, 0, stream>>>(qb, kb, vb, ab);
    transpose_cvt_kernel<<<16384, 256, 0, stream>>>(wo, Wt);
    gemm_dma<1><<<512, 256, 0, stream>>>(ab, Wt, d_out, 1.0f);
  } else {
    gemm_fb<0><<<512, 256, 0, stream>>>(xb, wq, qb, 0.125f);
    gemm_fb<0><<<512, 256, 0, stream>>>(xb, wk, kb, 1.0f);
    gemm_fb<0><<<512, 256, 0, stream>>>(xb, wv, vb, 1.0f);
    attn_kernel<<<1024, 256, 0, stream>>>(qb, kb, vb, ab);
    gemm_fb<1><<<512, 256, 0, stream>>>(ab, wo, d_out, 1.0f);
  }
}